// Round 9
// baseline (293.527 us; speedup 1.0000x reference)
//
#include <hip/hip_runtime.h>
#include <cstdint>
#include <cstddef>

#define B_ 64
#define P_ 24564
#define C_ 21
#define N_ 16
#define NPB_ 24          // blocks per batch: 24*1024 >= P_
#define THRESH_ 0.5f

// ---------------------------------------------------------------- helpers

__device__ inline unsigned long long shfl_down_u64(unsigned long long v, int off) {
    unsigned lo = (unsigned)v, hi = (unsigned)(v >> 32);
    lo = __shfl_down(lo, off);
    hi = __shfl_down(hi, off);
    return ((unsigned long long)hi << 32) | lo;
}

// smooth-L1 of (loc row - encoded(truth, prior)), summed over 4 coords
__device__ inline float sl1_encode(float4 ld, float4 pr,
                                   float tx1, float ty1, float tx2, float ty2) {
    float gcx = ((tx1 + tx2) * 0.5f - pr.x) / (0.1f * pr.z);
    float gcy = ((ty1 + ty2) * 0.5f - pr.y) / (0.1f * pr.w);
    float gw  = __logf((tx2 - tx1) / pr.z) / 0.2f;
    float gh  = __logf((ty2 - ty1) / pr.w) / 0.2f;
    float g[4] = {gcx, gcy, gw, gh};
    float l[4] = {ld.x, ld.y, ld.z, ld.w};
    float s = 0.0f;
#pragma unroll
    for (int i = 0; i < 4; i++) {
        float d = l[i] - g[i];
        float ad = fabsf(d);
        s += (ad < 1.0f) ? 0.5f * d * d : ad - 0.5f;
    }
    return s;
}

// ---------------------------------------------------------------- kernels

// kM: COMPUTE-ONLY match. Per-thread 4 priors: best-truth (first-max) ->
// packed byte (bti | pos<<4), 4 bytes = one coalesced u32 store. Also
// per-block best-prior argmax partials via skey LDS + wave reduce.
// No conf access, no big live ranges -> no spills.
__global__ __launch_bounds__(256, 4) void
kM_match(const float* __restrict__ priors,
         const float* __restrict__ truths,
         uint32_t* __restrict__ matchw,
         unsigned long long* __restrict__ part_key) {
    int b = blockIdx.y, bx = blockIdx.x, t = threadIdx.x;
    int wid = t >> 6, lane = t & 63;
    __shared__ float tr[N_ * 4];
    __shared__ unsigned skey[N_ * 256];      // 16 KB
    if (t < N_ * 4) tr[t] = truths[b * N_ * 4 + t];
    __syncthreads();

    int p0 = bx * 1024 + 4 * t;
    bool valid = p0 < P_;

    float px1[4], py1[4], px2[4], py2[4], ap[4];
#pragma unroll
    for (int r = 0; r < 4; r++) {
        float4 pr = valid ? ((const float4*)priors)[p0 + r]
                          : make_float4(0.5f, 0.5f, 0.1f, 0.1f);
        px1[r] = pr.x - pr.z * 0.5f; py1[r] = pr.y - pr.w * 0.5f;
        px2[r] = pr.x + pr.z * 0.5f; py2[r] = pr.y + pr.w * 0.5f;
        ap[r] = (px2[r] - px1[r]) * (py2[r] - py1[r]);
    }

    float best[4] = {-1.0f, -1.0f, -1.0f, -1.0f};
    int bn[4] = {0, 0, 0, 0};
#pragma unroll
    for (int n = 0; n < N_; n++) {
        float tx1 = tr[n * 4 + 0], ty1 = tr[n * 4 + 1];
        float tx2 = tr[n * 4 + 2], ty2 = tr[n * 4 + 3];
        float at = (tx2 - tx1) * (ty2 - ty1);
        float tbi = -1.0f;
        int tbr = 0;
#pragma unroll
        for (int r = 0; r < 4; r++) {
            float lx = fmaxf(tx1, px1[r]), ly = fmaxf(ty1, py1[r]);
            float rx = fminf(tx2, px2[r]), ry = fminf(ty2, py2[r]);
            float w = fmaxf(rx - lx, 0.0f), h = fmaxf(ry - ly, 0.0f);
            float inter = w * h;
            float iou = inter / (at + ap[r] - inter);
            if (iou > best[r]) { best[r] = iou; bn[r] = n; }
            if (iou > tbi) { tbi = iou; tbr = r; }     // smallest r on ties
        }
        // key32 = iou_bits<<2 | (3-r); invalid threads write 0.
        skey[n * 256 + t] = valid
            ? ((__float_as_uint(tbi) << 2) | (unsigned)(3 - tbr)) : 0u;
    }

    if (valid) {
        uint32_t w = 0;
#pragma unroll
        for (int r = 0; r < 4; r++) {
            uint32_t byte = (uint32_t)bn[r] | ((best[r] < THRESH_) ? 0u : 0x10u);
            w |= byte << (8 * r);
        }
        matchw[(size_t)b * (P_ / 4) + (p0 >> 2)] = w;
    }

    __syncthreads();
#pragma unroll
    for (int i = 0; i < 4; i++) {
        int n = wid + 4 * i;                 // wave w handles truths w,w+4,w+8,w+12
        unsigned long long bk = 0ull;
#pragma unroll
        for (int q = 0; q < 4; q++) {
            int tt = lane + 64 * q;
            unsigned k32 = skey[n * 256 + tt];
            unsigned long long v = ((unsigned long long)k32 << 32) |
                                   (unsigned)~(unsigned)tt;   // smallest t wins ties
            bk = (v > bk) ? v : bk;
        }
        for (int off = 32; off; off >>= 1) {
            unsigned long long o = shfl_down_u64(bk, off);
            bk = (o > bk) ? o : bk;
        }
        if (lane == 0) {
            int twin = (int)~(unsigned)(bk & 0xFFFFFFFFull);
            unsigned k32 = (unsigned)(bk >> 32);
            int pwin = bx * 1024 + 4 * twin + (3 - (int)(k32 & 3u));
            part_key[(size_t)(b * NPB_ + bx) * N_ + n] =
                ((unsigned long long)(k32 >> 2) << 32) | (unsigned)~(unsigned)pwin;
        }
    }
}

// kL: MEMORY-ONLY loss stream. Reads match word, streams conf as 21 float4
// exp-sums, gathers g, smooth-L1 on positives, writes mine + partials.
// No match VALU, no skey phase, tiny LDS, one barrier -> waves spend their
// life issuing loads.
__global__ __launch_bounds__(256, 4) void
kL_lse(const float* __restrict__ loc,
       const float* __restrict__ conf,
       const float* __restrict__ priors,
       const float* __restrict__ truths,
       const int* __restrict__ labels,
       const uint32_t* __restrict__ matchw,
       float* __restrict__ mine,
       float* __restrict__ part_ll,
       float* __restrict__ part_pce,
       int* __restrict__ part_np) {
    int b = blockIdx.y, bx = blockIdx.x, t = threadIdx.x;
    int wid = t >> 6, lane = t & 63;
    __shared__ float tr[N_ * 4];
    __shared__ int lb[N_];
    __shared__ float sll[4], spc[4];
    __shared__ int snp[4];
    if (t < N_ * 4) tr[t] = truths[b * N_ * 4 + t];
    if (t < N_) lb[t] = labels[b * N_ + t];
    __syncthreads();

    int p0 = bx * 1024 + 4 * t;
    bool valid = p0 < P_;

    uint32_t mw = valid ? matchw[(size_t)b * (P_ / 4) + (p0 >> 2)] : 0u;
    int bti[4], pos[4];
    float g[4];
    const float* cbase = conf + ((size_t)b * P_ + p0) * C_;
#pragma unroll
    for (int r = 0; r < 4; r++) {
        uint32_t byte = (mw >> (8 * r)) & 0xFFu;
        bti[r] = (int)(byte & 15u);
        pos[r] = (int)(byte >> 4);
        int cls = pos[r] ? (lb[bti[r]] + 1) : 0;
        g[r] = valid ? cbase[r * C_ + cls] : 0.0f;   // in flight with the stream
    }

    // streaming exp-sum; element e=4i+c belongs to row e/21 (compile-time).
    float s[4] = {0.0f, 0.0f, 0.0f, 0.0f};
    if (valid) {
        const float4* src = (const float4*)cbase;
#pragma unroll
        for (int i = 0; i < 21; i++) {
            float4 v = src[i];
            s[(4 * i + 0) / 21] += __expf(v.x);
            s[(4 * i + 1) / 21] += __expf(v.y);
            s[(4 * i + 2) / 21] += __expf(v.z);
            s[(4 * i + 3) / 21] += __expf(v.w);
        }
    }

    float ll = 0.0f, pce = 0.0f;
    int np = 0;
    if (valid) {
        float mv[4];
#pragma unroll
        for (int r = 0; r < 4; r++) {
            float lca = fmaxf(__logf(s[r]) - g[r], 0.0f);   // >= 0 by clamp
            mv[r] = pos[r] ? 0.0f : lca;
            if (pos[r]) {
                np++;
                pce += lca;
                float4 prr = ((const float4*)priors)[p0 + r];
                float4 ld = ((const float4*)loc)[(size_t)b * P_ + p0 + r];
                ll += sl1_encode(ld, prr, tr[bti[r] * 4 + 0], tr[bti[r] * 4 + 1],
                                 tr[bti[r] * 4 + 2], tr[bti[r] * 4 + 3]);
            }
        }
        *(float4*)(mine + (size_t)b * P_ + p0) = make_float4(mv[0], mv[1], mv[2], mv[3]);
    }

    for (int off = 32; off; off >>= 1) {
        ll += __shfl_down(ll, off);
        pce += __shfl_down(pce, off);
        np += __shfl_down(np, off);
    }
    if (lane == 0) { sll[wid] = ll; spc[wid] = pce; snp[wid] = np; }
    __syncthreads();
    if (t == 0) {
        float a = 0.0f, cc = 0.0f;
        int q = 0;
        for (int i = 0; i < 4; i++) { a += sll[i]; cc += spc[i]; q += snp[i]; }
        part_ll[b * NPB_ + bx] = a;
        part_pce[b * NPB_ + bx] = cc;
        part_np[b * NPB_ + bx] = q;
    }
}

// kB: one block per batch. Reduce argmax partials -> sp[]; parallel
// last-occurrence override deltas; top-k via 31-round bitwise threshold
// search (register compares, no LDS atomics). Unchanged from R8.
__global__ __launch_bounds__(1024) void
kB_batch(const float* __restrict__ loc,
         const float* __restrict__ conf,
         const float* __restrict__ priors,
         const float* __restrict__ truths,
         const int* __restrict__ labels,
         const float* __restrict__ mine,
         const float* __restrict__ part_ll,
         const float* __restrict__ part_pce,
         const int* __restrict__ part_np,
         const unsigned long long* __restrict__ part_key,
         double* __restrict__ bll,
         double* __restrict__ bpc,
         int* __restrict__ bnp) {
    int b = blockIdx.x, t = threadIdx.x, wid = t >> 6, lane = t & 63;
    __shared__ float tr[N_ * 4];
    __shared__ int lb[N_];
    __shared__ int sp[N_];
    __shared__ float sdll, sdpce, sll_s, spc_s;
    __shared__ int sdnp, snp_s;
    __shared__ int scnt[16];
    __shared__ unsigned sT;
    __shared__ float wsum[16];
    __shared__ int wcgt[16];

    if (t < N_ * 4) tr[t] = truths[b * N_ * 4 + t];
    if (t < N_) lb[t] = labels[b * N_ + t];
    if (t == 0) { sdll = 0.f; sdpce = 0.f; sdnp = 0; sll_s = 0.f; spc_s = 0.f; snp_s = 0; }
    if (t < N_) {                                  // phase 1: bpi reduce
        unsigned long long best = 0ull;
        for (int i = 0; i < NPB_; i++) {
            unsigned long long k = part_key[(size_t)(b * NPB_ + i) * N_ + t];
            best = (k > best) ? k : best;
        }
        sp[t] = (int)~(unsigned)(best & 0xFFFFFFFFull);
    }
    __syncthreads();
    if (t < NPB_) {                                // partial-sum gather
        atomicAdd(&sll_s, part_ll[b * NPB_ + t]);
        atomicAdd(&spc_s, part_pce[b * NPB_ + t]);
        atomicAdd(&snp_s, part_np[b * NPB_ + t]);
    }
    // override deltas: (t, sp[t]) contributes iff t is the LAST truth
    // mapping to this prior (sequential last-wins semantics).
    if (t < N_) {
        int p = sp[t];
        bool last = true;
        for (int n = t + 1; n < N_; n++) if (sp[n] == p) last = false;
        if (last) {
            int nf = t;
            float4 pr = ((const float4*)priors)[p];
            float px1 = pr.x - pr.z * 0.5f, py1 = pr.y - pr.w * 0.5f;
            float px2 = pr.x + pr.z * 0.5f, py2 = pr.y + pr.w * 0.5f;
            float ap = (px2 - px1) * (py2 - py1);
            float best = -1.0f;
            int bti = 0;
            for (int n = 0; n < N_; n++) {
                float tx1 = tr[n * 4], ty1 = tr[n * 4 + 1];
                float tx2 = tr[n * 4 + 2], ty2 = tr[n * 4 + 3];
                float at = (tx2 - tx1) * (ty2 - ty1);
                float lx = fmaxf(tx1, px1), ly = fmaxf(ty1, py1);
                float rx = fminf(tx2, px2), ry = fminf(ty2, py2);
                float w = fmaxf(rx - lx, 0.0f), h = fmaxf(ry - ly, 0.0f);
                float inter = w * h;
                float iou = inter / (at + ap - inter);
                if (iou > best) { best = iou; bti = n; }
            }
            int pos_old = (best >= THRESH_) ? 1 : 0;
            const float* cp = conf + ((size_t)b * P_ + p) * C_;
            float x[C_];
            float ssum = 0.0f;
            for (int j = 0; j < C_; j++) { x[j] = cp[j]; ssum += __expf(x[j]); }
            float lse = __logf(ssum);
            float4 ld = ((const float4*)loc)[(size_t)b * P_ + p];
            float dll = sl1_encode(ld, pr, tr[nf * 4], tr[nf * 4 + 1],
                                   tr[nf * 4 + 2], tr[nf * 4 + 3]);
            float dpce = lse - x[lb[nf] + 1];
            int dnp = 1 - pos_old;
            if (pos_old) {
                dll -= sl1_encode(ld, pr, tr[bti * 4], tr[bti * 4 + 1],
                                  tr[bti * 4 + 2], tr[bti * 4 + 3]);
                dpce -= lse - x[lb[bti] + 1];
            }
            atomicAdd(&sdll, dll);
            atomicAdd(&sdpce, dpce);
            atomicAdd(&sdnp, dnp);
        }
    }

    // per-thread override bitmask + register-cached values
    unsigned omask = 0;
#pragma unroll
    for (int n = 0; n < N_; n++) {
        int p = sp[n];
        if ((p & 1023) == t) omask |= 1u << (p >> 10);
    }
    const float* v = mine + (size_t)b * P_;
    int nel = (t < (P_ - 23 * 1024)) ? 24 : 23;
    float xv[24];
#pragma unroll
    for (int i = 0; i < 24; i++) {
        float x = 0.0f;
        if (i < nel) x = v[t + (i << 10)];
        if ((omask >> i) & 1) x = 0.0f;          // overridden -> positive -> 0
        xv[i] = x;
    }
    __syncthreads();                             // sdnp/snp_s complete
    int np = snp_s + sdnp;
    int k = np * 3;
    if (k > P_ - 1) k = P_ - 1;

    // bitwise threshold search: T ends as the k-th largest bit pattern.
    unsigned T = 0u;
    for (int bpos = 30; bpos >= 0; bpos--) {
        unsigned cand = T | (1u << bpos);
        int c = 0;
#pragma unroll
        for (int i = 0; i < 24; i++)
            if (__float_as_uint(xv[i]) >= cand) c++;
        for (int off = 32; off; off >>= 1) c += __shfl_down(c, off);
        if (lane == 0) scnt[wid] = c;
        __syncthreads();
        if (t == 0) {
            int tot = 0;
            for (int i = 0; i < 16; i++) tot += scnt[i];
            sT = (tot >= k) ? cand : T;
        }
        __syncthreads();
        T = sT;
    }

    float psum = 0.0f;
    int cgt = 0;
#pragma unroll
    for (int i = 0; i < 24; i++) {
        if (__float_as_uint(xv[i]) > T) { psum += xv[i]; cgt++; }
    }
    for (int off = 32; off; off >>= 1) {
        psum += __shfl_down(psum, off);
        cgt += __shfl_down(cgt, off);
    }
    if (lane == 0) { wsum[wid] = psum; wcgt[wid] = cgt; }
    __syncthreads();
    if (t == 0) {
        float s2 = 0.0f;
        int cg = 0;
        for (int i = 0; i < 16; i++) { s2 += wsum[i]; cg += wcgt[i]; }
        int skrem = k - cg;                      // >= 0 by construction
        double tot = (double)s2 + (double)skrem * (double)__uint_as_float(T);
        bll[b] = (double)(sll_s + sdll);
        bpc[b] = (double)(spc_s + sdpce) + tot;
        bnp[b] = np;
    }
}

// kC: final 64-wide reduce.
__global__ void kC_final(const double* __restrict__ bll,
                         const double* __restrict__ bpc,
                         const int* __restrict__ bnp,
                         float* __restrict__ out) {
    int t = threadIdx.x;  // 64 threads
    double a = bll[t], c = bpc[t];
    int n = bnp[t];
    for (int off = 32; off; off >>= 1) {
        a += __shfl_down(a, off);
        c += __shfl_down(c, off);
        n += __shfl_down(n, off);
    }
    if (t == 0) {
        double dn = (double)n;
        out[0] = (float)(a / dn);
        out[1] = (float)(c / dn);
    }
}

// ---------------------------------------------------------------- launch

extern "C" void kernel_launch(void* const* d_in, const int* in_sizes, int n_in,
                              void* d_out, int out_size, void* d_ws, size_t ws_size,
                              hipStream_t stream) {
    const float* loc    = (const float*)d_in[0];
    const float* conf   = (const float*)d_in[1];
    const float* priors = (const float*)d_in[2];
    const float* truths = (const float*)d_in[3];
    const int*   labels = (const int*)d_in[4];
    float* out = (float*)d_out;

    char* ws = (char*)d_ws;
    // layout:
    //   [0      .. 196608)   part_key: 1536*16 u64
    //   [196608 .. 202752)   part_ll:  1536 floats
    //   [202752 .. 208896)   part_pce: 1536 floats
    //   [208896 .. 215040)   part_np:  1536 ints
    //   [215040 .. 215552)   bll: 64 doubles
    //   [215552 .. 216064)   bpc: 64 doubles
    //   [216064 .. 216320)   bnp: 64 ints
    //   [262144 .. 6550528)  mine: B*P floats
    //   [6553600 .. 8126464) matchw: B*(P/4) u32
    unsigned long long* part_key = (unsigned long long*)(ws);
    float*  part_ll  = (float*)(ws + 196608);
    float*  part_pce = (float*)(ws + 202752);
    int*    part_np  = (int*)(ws + 208896);
    double* bll      = (double*)(ws + 215040);
    double* bpc      = (double*)(ws + 215552);
    int*    bnp      = (int*)(ws + 216064);
    float*  mine     = (float*)(ws + 262144);
    uint32_t* matchw = (uint32_t*)(ws + 6553600);

    hipLaunchKernelGGL(kM_match, dim3(NPB_, B_), dim3(256), 0, stream,
                       priors, truths, matchw, part_key);
    hipLaunchKernelGGL(kL_lse, dim3(NPB_, B_), dim3(256), 0, stream,
                       loc, conf, priors, truths, labels, matchw,
                       mine, part_ll, part_pce, part_np);
    hipLaunchKernelGGL(kB_batch, dim3(B_), dim3(1024), 0, stream,
                       loc, conf, priors, truths, labels, mine,
                       part_ll, part_pce, part_np, part_key, bll, bpc, bnp);
    hipLaunchKernelGGL(kC_final, dim3(1), dim3(64), 0, stream, bll, bpc, bnp, out);
}

// Round 10
// 279.083 us; speedup vs baseline: 1.0518x; 1.0518x over previous
//
#include <hip/hip_runtime.h>
#include <cstdint>
#include <cstddef>

#define B_ 64
#define P_ 24564
#define C_ 21
#define N_ 16
#define NPB_ 24          // kM blocks per batch: 24*1024 >= P_
#define NPL_ 96          // kL blocks per batch: 96*256  >= P_
#define THRESH_ 0.5f

// ---------------------------------------------------------------- helpers

__device__ inline unsigned long long shfl_down_u64(unsigned long long v, int off) {
    unsigned lo = (unsigned)v, hi = (unsigned)(v >> 32);
    lo = __shfl_down(lo, off);
    hi = __shfl_down(hi, off);
    return ((unsigned long long)hi << 32) | lo;
}

// async global->LDS, 16 B per lane; LDS dest is wave-uniform base + lane*16
__device__ inline void async_copy16(const float* g, float* l) {
    __builtin_amdgcn_global_load_lds(
        (const __attribute__((address_space(1))) void*)g,
        (__attribute__((address_space(3))) void*)l, 16, 0, 0);
}

// smooth-L1 of (loc row - encoded(truth, prior)), summed over 4 coords
__device__ inline float sl1_encode(float4 ld, float4 pr,
                                   float tx1, float ty1, float tx2, float ty2) {
    float gcx = ((tx1 + tx2) * 0.5f - pr.x) / (0.1f * pr.z);
    float gcy = ((ty1 + ty2) * 0.5f - pr.y) / (0.1f * pr.w);
    float gw  = __logf((tx2 - tx1) / pr.z) / 0.2f;
    float gh  = __logf((ty2 - ty1) / pr.w) / 0.2f;
    float g[4] = {gcx, gcy, gw, gh};
    float l[4] = {ld.x, ld.y, ld.z, ld.w};
    float s = 0.0f;
#pragma unroll
    for (int i = 0; i < 4; i++) {
        float d = l[i] - g[i];
        float ad = fabsf(d);
        s += (ad < 1.0f) ? 0.5f * d * d : ad - 0.5f;
    }
    return s;
}

// ---------------------------------------------------------------- kernels

// kM: COMPUTE-ONLY match (unchanged from R9). 4 priors/thread, packed match
// byte per prior -> one coalesced u32 store; per-block argmax partials.
__global__ __launch_bounds__(256, 4) void
kM_match(const float* __restrict__ priors,
         const float* __restrict__ truths,
         uint32_t* __restrict__ matchw,
         unsigned long long* __restrict__ part_key) {
    int b = blockIdx.y, bx = blockIdx.x, t = threadIdx.x;
    int wid = t >> 6, lane = t & 63;
    __shared__ float tr[N_ * 4];
    __shared__ unsigned skey[N_ * 256];      // 16 KB
    if (t < N_ * 4) tr[t] = truths[b * N_ * 4 + t];
    __syncthreads();

    int p0 = bx * 1024 + 4 * t;
    bool valid = p0 < P_;

    float px1[4], py1[4], px2[4], py2[4], ap[4];
#pragma unroll
    for (int r = 0; r < 4; r++) {
        float4 pr = valid ? ((const float4*)priors)[p0 + r]
                          : make_float4(0.5f, 0.5f, 0.1f, 0.1f);
        px1[r] = pr.x - pr.z * 0.5f; py1[r] = pr.y - pr.w * 0.5f;
        px2[r] = pr.x + pr.z * 0.5f; py2[r] = pr.y + pr.w * 0.5f;
        ap[r] = (px2[r] - px1[r]) * (py2[r] - py1[r]);
    }

    float best[4] = {-1.0f, -1.0f, -1.0f, -1.0f};
    int bn[4] = {0, 0, 0, 0};
#pragma unroll
    for (int n = 0; n < N_; n++) {
        float tx1 = tr[n * 4 + 0], ty1 = tr[n * 4 + 1];
        float tx2 = tr[n * 4 + 2], ty2 = tr[n * 4 + 3];
        float at = (tx2 - tx1) * (ty2 - ty1);
        float tbi = -1.0f;
        int tbr = 0;
#pragma unroll
        for (int r = 0; r < 4; r++) {
            float lx = fmaxf(tx1, px1[r]), ly = fmaxf(ty1, py1[r]);
            float rx = fminf(tx2, px2[r]), ry = fminf(ty2, py2[r]);
            float w = fmaxf(rx - lx, 0.0f), h = fmaxf(ry - ly, 0.0f);
            float inter = w * h;
            float iou = inter / (at + ap[r] - inter);
            if (iou > best[r]) { best[r] = iou; bn[r] = n; }
            if (iou > tbi) { tbi = iou; tbr = r; }     // smallest r on ties
        }
        skey[n * 256 + t] = valid
            ? ((__float_as_uint(tbi) << 2) | (unsigned)(3 - tbr)) : 0u;
    }

    if (valid) {
        uint32_t w = 0;
#pragma unroll
        for (int r = 0; r < 4; r++) {
            uint32_t byte = (uint32_t)bn[r] | ((best[r] < THRESH_) ? 0u : 0x10u);
            w |= byte << (8 * r);
        }
        matchw[(size_t)b * (P_ / 4) + (p0 >> 2)] = w;
    }

    __syncthreads();
#pragma unroll
    for (int i = 0; i < 4; i++) {
        int n = wid + 4 * i;
        unsigned long long bk = 0ull;
#pragma unroll
        for (int q = 0; q < 4; q++) {
            int tt = lane + 64 * q;
            unsigned k32 = skey[n * 256 + tt];
            unsigned long long v = ((unsigned long long)k32 << 32) |
                                   (unsigned)~(unsigned)tt;
            bk = (v > bk) ? v : bk;
        }
        for (int off = 32; off; off >>= 1) {
            unsigned long long o = shfl_down_u64(bk, off);
            bk = (o > bk) ? o : bk;
        }
        if (lane == 0) {
            int twin = (int)~(unsigned)(bk & 0xFFFFFFFFull);
            unsigned k32 = (unsigned)(bk >> 32);
            int pwin = bx * 1024 + 4 * twin + (3 - (int)(k32 & 3u));
            part_key[(size_t)(b * NPB_ + bx) * N_ + n] =
                ((unsigned long long)(k32 >> 2) << 32) | (unsigned)~(unsigned)pwin;
        }
    }
}

// kL: COALESCED loss stream. Block = 256 priors. conf tile (21504 B) staged
// to LDS via async global_load_lds width-16 (contiguous, coalesced: each
// wave instr touches 16 lines, not 64 as the old 336B-lane-stride did).
// Then per-thread row read from LDS (stride 21 dwords = conflict-free).
__global__ __launch_bounds__(256, 6) void
kL_lse(const float* __restrict__ loc,
       const float* __restrict__ conf,
       const float* __restrict__ priors,
       const float* __restrict__ truths,
       const int* __restrict__ labels,
       const uint32_t* __restrict__ matchw,
       float* __restrict__ mine,
       float* __restrict__ part_ll,
       float* __restrict__ part_pce,
       int* __restrict__ part_np) {
    int b = blockIdx.y, bx = blockIdx.x, t = threadIdx.x;
    int wid = t >> 6, lane = t & 63;
    __shared__ float scf[256 * C_];          // 21504 B conf tile
    __shared__ float tr[N_ * 4];
    __shared__ int lb[N_];
    __shared__ float sll[4], spc[4];
    __shared__ int snp[4];
    if (t < N_ * 4) tr[t] = truths[b * N_ * 4 + t];
    if (t < N_) lb[t] = labels[b * N_ + t];

    int base_p = bx * 256;
    int nvalid = min(256, P_ - base_p);      // 256, or 244 in the last block
    int maxf4 = (nvalid * C_) >> 2;          // valid float4s in tile (%4==0)
    const float* gtile = conf + ((size_t)b * P_ + base_p) * C_;  // f4-aligned

    // async staging: instruction k (0..20) by wave k%4; 64 lanes x 16 B each
    for (int k = wid; k < 21; k += 4) {
        int f4 = k * 64 + lane;
        int s4 = (f4 < maxf4) ? f4 : (maxf4 - 1);   // clamp: no OOB, dup data
        async_copy16(gtile + (size_t)s4 * 4, scf + k * 256);
    }
    __syncthreads();                         // drains vmcnt -> tile complete

    int p0 = base_p + t;
    bool valid = t < nvalid;

    float ll = 0.0f, pce = 0.0f;
    int np = 0;
    if (valid) {
        uint32_t mwv = matchw[(size_t)b * (P_ / 4) + (p0 >> 2)];
        uint32_t byte = (mwv >> (8 * (p0 & 3))) & 0xFFu;
        int bti = (int)(byte & 15u);
        int pos = (int)(byte >> 4);
        int cls = pos ? (lb[bti] + 1) : 0;

        float ssum = 0.0f;
#pragma unroll
        for (int i = 0; i < 21; i++) ssum += __expf(scf[t * 21 + i]);
        float g = scf[t * 21 + cls];
        float lca = fmaxf(__logf(ssum) - g, 0.0f);   // >= 0 by clamp

        mine[(size_t)b * P_ + p0] = pos ? 0.0f : lca;  // coalesced dword

        if (pos) {
            np = 1;
            pce = lca;
            float4 prr = ((const float4*)priors)[p0];
            float4 ld = ((const float4*)loc)[(size_t)b * P_ + p0];
            ll = sl1_encode(ld, prr, tr[bti * 4 + 0], tr[bti * 4 + 1],
                            tr[bti * 4 + 2], tr[bti * 4 + 3]);
        }
    }

    for (int off = 32; off; off >>= 1) {
        ll += __shfl_down(ll, off);
        pce += __shfl_down(pce, off);
        np += __shfl_down(np, off);
    }
    if (lane == 0) { sll[wid] = ll; spc[wid] = pce; snp[wid] = np; }
    __syncthreads();
    if (t == 0) {
        float a = 0.0f, cc = 0.0f;
        int q = 0;
        for (int i = 0; i < 4; i++) { a += sll[i]; cc += spc[i]; q += snp[i]; }
        part_ll[b * NPL_ + bx] = a;
        part_pce[b * NPL_ + bx] = cc;
        part_np[b * NPL_ + bx] = q;
    }
}

// kB: one block per batch. Reduce argmax partials -> sp[]; parallel
// last-occurrence override deltas; top-k via 31-round bitwise threshold
// search (register compares, no LDS atomics).
__global__ __launch_bounds__(1024) void
kB_batch(const float* __restrict__ loc,
         const float* __restrict__ conf,
         const float* __restrict__ priors,
         const float* __restrict__ truths,
         const int* __restrict__ labels,
         const float* __restrict__ mine,
         const float* __restrict__ part_ll,
         const float* __restrict__ part_pce,
         const int* __restrict__ part_np,
         const unsigned long long* __restrict__ part_key,
         double* __restrict__ bll,
         double* __restrict__ bpc,
         int* __restrict__ bnp) {
    int b = blockIdx.x, t = threadIdx.x, wid = t >> 6, lane = t & 63;
    __shared__ float tr[N_ * 4];
    __shared__ int lb[N_];
    __shared__ int sp[N_];
    __shared__ float sdll, sdpce, sll_s, spc_s;
    __shared__ int sdnp, snp_s;
    __shared__ int scnt[16];
    __shared__ unsigned sT;
    __shared__ float wsum[16];
    __shared__ int wcgt[16];

    if (t < N_ * 4) tr[t] = truths[b * N_ * 4 + t];
    if (t < N_) lb[t] = labels[b * N_ + t];
    if (t == 0) { sdll = 0.f; sdpce = 0.f; sdnp = 0; sll_s = 0.f; spc_s = 0.f; snp_s = 0; }
    if (t < N_) {                                  // phase 1: bpi reduce
        unsigned long long best = 0ull;
        for (int i = 0; i < NPB_; i++) {
            unsigned long long k = part_key[(size_t)(b * NPB_ + i) * N_ + t];
            best = (k > best) ? k : best;
        }
        sp[t] = (int)~(unsigned)(best & 0xFFFFFFFFull);
    }
    __syncthreads();
    if (t < NPL_) {                                // partial-sum gather
        atomicAdd(&sll_s, part_ll[b * NPL_ + t]);
        atomicAdd(&spc_s, part_pce[b * NPL_ + t]);
        atomicAdd(&snp_s, part_np[b * NPL_ + t]);
    }
    // override deltas: (t, sp[t]) contributes iff t is the LAST truth
    // mapping to this prior (sequential last-wins semantics).
    if (t < N_) {
        int p = sp[t];
        bool last = true;
        for (int n = t + 1; n < N_; n++) if (sp[n] == p) last = false;
        if (last) {
            int nf = t;
            float4 pr = ((const float4*)priors)[p];
            float px1 = pr.x - pr.z * 0.5f, py1 = pr.y - pr.w * 0.5f;
            float px2 = pr.x + pr.z * 0.5f, py2 = pr.y + pr.w * 0.5f;
            float ap = (px2 - px1) * (py2 - py1);
            float best = -1.0f;
            int bti = 0;
            for (int n = 0; n < N_; n++) {
                float tx1 = tr[n * 4], ty1 = tr[n * 4 + 1];
                float tx2 = tr[n * 4 + 2], ty2 = tr[n * 4 + 3];
                float at = (tx2 - tx1) * (ty2 - ty1);
                float lx = fmaxf(tx1, px1), ly = fmaxf(ty1, py1);
                float rx = fminf(tx2, px2), ry = fminf(ty2, py2);
                float w = fmaxf(rx - lx, 0.0f), h = fmaxf(ry - ly, 0.0f);
                float inter = w * h;
                float iou = inter / (at + ap - inter);
                if (iou > best) { best = iou; bti = n; }
            }
            int pos_old = (best >= THRESH_) ? 1 : 0;
            const float* cp = conf + ((size_t)b * P_ + p) * C_;
            float x[C_];
            float ssum = 0.0f;
            for (int j = 0; j < C_; j++) { x[j] = cp[j]; ssum += __expf(x[j]); }
            float lse = __logf(ssum);
            float4 ld = ((const float4*)loc)[(size_t)b * P_ + p];
            float dll = sl1_encode(ld, pr, tr[nf * 4], tr[nf * 4 + 1],
                                   tr[nf * 4 + 2], tr[nf * 4 + 3]);
            float dpce = lse - x[lb[nf] + 1];
            int dnp = 1 - pos_old;
            if (pos_old) {
                dll -= sl1_encode(ld, pr, tr[bti * 4], tr[bti * 4 + 1],
                                  tr[bti * 4 + 2], tr[bti * 4 + 3]);
                dpce -= lse - x[lb[bti] + 1];
            }
            atomicAdd(&sdll, dll);
            atomicAdd(&sdpce, dpce);
            atomicAdd(&sdnp, dnp);
        }
    }

    // per-thread override bitmask + register-cached values
    unsigned omask = 0;
#pragma unroll
    for (int n = 0; n < N_; n++) {
        int p = sp[n];
        if ((p & 1023) == t) omask |= 1u << (p >> 10);
    }
    const float* v = mine + (size_t)b * P_;
    int nel = (t < (P_ - 23 * 1024)) ? 24 : 23;
    float xv[24];
#pragma unroll
    for (int i = 0; i < 24; i++) {
        float x = 0.0f;
        if (i < nel) x = v[t + (i << 10)];
        if ((omask >> i) & 1) x = 0.0f;          // overridden -> positive -> 0
        xv[i] = x;
    }
    __syncthreads();                             // sdnp/snp_s complete
    int np = snp_s + sdnp;
    int k = np * 3;
    if (k > P_ - 1) k = P_ - 1;

    // bitwise threshold search: T ends as the k-th largest bit pattern.
    unsigned T = 0u;
    for (int bpos = 30; bpos >= 0; bpos--) {
        unsigned cand = T | (1u << bpos);
        int c = 0;
#pragma unroll
        for (int i = 0; i < 24; i++)
            if (__float_as_uint(xv[i]) >= cand) c++;
        for (int off = 32; off; off >>= 1) c += __shfl_down(c, off);
        if (lane == 0) scnt[wid] = c;
        __syncthreads();
        if (t == 0) {
            int tot = 0;
            for (int i = 0; i < 16; i++) tot += scnt[i];
            sT = (tot >= k) ? cand : T;
        }
        __syncthreads();
        T = sT;
    }

    float psum = 0.0f;
    int cgt = 0;
#pragma unroll
    for (int i = 0; i < 24; i++) {
        if (__float_as_uint(xv[i]) > T) { psum += xv[i]; cgt++; }
    }
    for (int off = 32; off; off >>= 1) {
        psum += __shfl_down(psum, off);
        cgt += __shfl_down(cgt, off);
    }
    if (lane == 0) { wsum[wid] = psum; wcgt[wid] = cgt; }
    __syncthreads();
    if (t == 0) {
        float s2 = 0.0f;
        int cg = 0;
        for (int i = 0; i < 16; i++) { s2 += wsum[i]; cg += wcgt[i]; }
        int skrem = k - cg;                      // >= 0 by construction
        double tot = (double)s2 + (double)skrem * (double)__uint_as_float(T);
        bll[b] = (double)(sll_s + sdll);
        bpc[b] = (double)(spc_s + sdpce) + tot;
        bnp[b] = np;
    }
}

// kC: final 64-wide reduce.
__global__ void kC_final(const double* __restrict__ bll,
                         const double* __restrict__ bpc,
                         const int* __restrict__ bnp,
                         float* __restrict__ out) {
    int t = threadIdx.x;  // 64 threads
    double a = bll[t], c = bpc[t];
    int n = bnp[t];
    for (int off = 32; off; off >>= 1) {
        a += __shfl_down(a, off);
        c += __shfl_down(c, off);
        n += __shfl_down(n, off);
    }
    if (t == 0) {
        double dn = (double)n;
        out[0] = (float)(a / dn);
        out[1] = (float)(c / dn);
    }
}

// ---------------------------------------------------------------- launch

extern "C" void kernel_launch(void* const* d_in, const int* in_sizes, int n_in,
                              void* d_out, int out_size, void* d_ws, size_t ws_size,
                              hipStream_t stream) {
    const float* loc    = (const float*)d_in[0];
    const float* conf   = (const float*)d_in[1];
    const float* priors = (const float*)d_in[2];
    const float* truths = (const float*)d_in[3];
    const int*   labels = (const int*)d_in[4];
    float* out = (float*)d_out;

    char* ws = (char*)d_ws;
    // layout:
    //   [0       .. 196608)   part_key: 24*64*16 u64
    //   [196608  .. 221184)   part_ll:  96*64 floats
    //   [221184  .. 245760)   part_pce: 96*64 floats
    //   [245760  .. 270336)   part_np:  96*64 ints
    //   [270336  .. 270848)   bll: 64 doubles
    //   [270848  .. 271360)   bpc: 64 doubles
    //   [271360  .. 271616)   bnp: 64 ints
    //   [294912  .. 6583296)  mine: B*P floats
    //   [6583296 .. 8156160)  matchw: B*(P/4) u32
    unsigned long long* part_key = (unsigned long long*)(ws);
    float*  part_ll  = (float*)(ws + 196608);
    float*  part_pce = (float*)(ws + 221184);
    int*    part_np  = (int*)(ws + 245760);
    double* bll      = (double*)(ws + 270336);
    double* bpc      = (double*)(ws + 270848);
    int*    bnp      = (int*)(ws + 271360);
    float*  mine     = (float*)(ws + 294912);
    uint32_t* matchw = (uint32_t*)(ws + 6583296);

    hipLaunchKernelGGL(kM_match, dim3(NPB_, B_), dim3(256), 0, stream,
                       priors, truths, matchw, part_key);
    hipLaunchKernelGGL(kL_lse, dim3(NPL_, B_), dim3(256), 0, stream,
                       loc, conf, priors, truths, labels, matchw,
                       mine, part_ll, part_pce, part_np);
    hipLaunchKernelGGL(kB_batch, dim3(B_), dim3(1024), 0, stream,
                       loc, conf, priors, truths, labels, mine,
                       part_ll, part_pce, part_np, part_key, bll, bpc, bnp);
    hipLaunchKernelGGL(kC_final, dim3(1), dim3(64), 0, stream, bll, bpc, bnp, out);
}

// Round 11
// 258.899 us; speedup vs baseline: 1.1338x; 1.0780x over previous
//
#include <hip/hip_runtime.h>
#include <cstdint>
#include <cstddef>

#define B_ 64
#define P_ 24564
#define C_ 21
#define N_ 16
#define NPL_ 96          // kF blocks per batch: 96*256 >= P_
#define THRESH_ 0.5f

// ---------------------------------------------------------------- helpers

__device__ inline unsigned long long shfl_down_u64(unsigned long long v, int off) {
    unsigned lo = (unsigned)v, hi = (unsigned)(v >> 32);
    lo = __shfl_down(lo, off);
    hi = __shfl_down(hi, off);
    return ((unsigned long long)hi << 32) | lo;
}

// async global->LDS, 16 B per lane; LDS dest is wave-uniform base + lane*16
__device__ inline void async_copy16(const float* g, float* l) {
    __builtin_amdgcn_global_load_lds(
        (const __attribute__((address_space(1))) void*)g,
        (__attribute__((address_space(3))) void*)l, 16, 0, 0);
}

// smooth-L1 of (loc row - encoded(truth, prior)), summed over 4 coords
__device__ inline float sl1_encode(float4 ld, float4 pr,
                                   float tx1, float ty1, float tx2, float ty2) {
    float gcx = ((tx1 + tx2) * 0.5f - pr.x) / (0.1f * pr.z);
    float gcy = ((ty1 + ty2) * 0.5f - pr.y) / (0.1f * pr.w);
    float gw  = __logf((tx2 - tx1) / pr.z) / 0.2f;
    float gh  = __logf((ty2 - ty1) / pr.w) / 0.2f;
    float g[4] = {gcx, gcy, gw, gh};
    float l[4] = {ld.x, ld.y, ld.z, ld.w};
    float s = 0.0f;
#pragma unroll
    for (int i = 0; i < 4; i++) {
        float d = l[i] - g[i];
        float ad = fabsf(d);
        s += (ad < 1.0f) ? 0.5f * d * d : ad - 0.5f;
    }
    return s;
}

// ---------------------------------------------------------------- kernels

// kF: FUSED match + loss. Block = 256 priors (1/thread).
// Order: (1) issue async conf-tile staging (21 global_load_lds width-16,
// coalesced); (2) while in flight: match compute with UNIFORM truth loads
// (scalar, no pre-barrier needed) + skey writes; (3) one barrier drains
// staging + skey + lb; (4) per-block argmax reduce, LSE from LDS (stride-21
// rows = conflict-free), smooth-L1, partial outputs. No matchw round trip.
__global__ __launch_bounds__(256, 4) void
kF_fused(const float* __restrict__ loc,
         const float* __restrict__ conf,
         const float* __restrict__ priors,
         const float* __restrict__ truths,
         const int* __restrict__ labels,
         float* __restrict__ mine,
         float* __restrict__ part_ll,
         float* __restrict__ part_pce,
         int* __restrict__ part_np,
         unsigned long long* __restrict__ part_key) {
    int b = blockIdx.y, bx = blockIdx.x, t = threadIdx.x;
    int wid = t >> 6, lane = t & 63;
    __shared__ float scf[256 * C_];          // 21504 B conf tile
    __shared__ unsigned skey[N_ * 256];      // 16 KB per-(truth,thread) key32
    __shared__ int lb[N_];
    __shared__ float sll[4], spc[4];
    __shared__ int snp[4];

    int base_p = bx * 256;
    int nvalid = min(256, P_ - base_p);      // 256, or 244 in the last block
    int maxf4 = (nvalid * C_) >> 2;
    const float* gtile = conf + ((size_t)b * P_ + base_p) * C_;  // 16B-aligned

    // (1) async staging first: wave k%4 issues instr k; 64 lanes x 16 B
    for (int k = wid; k < 21; k += 4) {
        int f4 = k * 64 + lane;
        int s4 = (f4 < maxf4) ? f4 : (maxf4 - 1);   // clamp: no OOB
        async_copy16(gtile + (size_t)s4 * 4, scf + k * 256);
    }
    if (t < N_) lb[t] = labels[b * N_ + t];  // visible after the barrier

    // (2) match compute overlapping the staging latency
    int p0 = base_p + t;
    bool valid = t < nvalid;
    float4 pr = ((const float4*)priors)[valid ? p0 : base_p];
    float px1 = pr.x - pr.z * 0.5f, py1 = pr.y - pr.w * 0.5f;
    float px2 = pr.x + pr.z * 0.5f, py2 = pr.y + pr.w * 0.5f;
    float ap = (px2 - px1) * (py2 - py1);

    float best = -1.0f;
    int bn = 0;
#pragma unroll
    for (int n = 0; n < N_; n++) {
        float4 tb = ((const float4*)truths)[b * N_ + n];   // uniform -> s_load
        float at = (tb.z - tb.x) * (tb.w - tb.y);
        float lx = fmaxf(tb.x, px1), ly = fmaxf(tb.y, py1);
        float rx = fminf(tb.z, px2), ry = fminf(tb.w, py2);
        float w = fmaxf(rx - lx, 0.0f), h = fmaxf(ry - ly, 0.0f);
        float inter = w * h;
        float iou = inter / (at + ap - inter);
        if (iou > best) { best = iou; bn = n; }
        skey[n * 256 + t] = valid ? __float_as_uint(iou) : 0u;
    }
    int pos = (valid && best >= THRESH_) ? 1 : 0;

    // (3) one barrier: drains async staging (vmcnt) + skey/lb (lgkm)
    __syncthreads();

    // (4a) per-block best-prior argmax partials: wave w -> truths w,w+4,w+8,w+12
#pragma unroll
    for (int i = 0; i < 4; i++) {
        int n = wid + 4 * i;
        unsigned long long bk = 0ull;
#pragma unroll
        for (int q = 0; q < 4; q++) {
            int tt = lane + 64 * q;
            unsigned k32 = skey[n * 256 + tt];
            unsigned long long v = ((unsigned long long)k32 << 32) |
                                   (unsigned)~(unsigned)tt;   // smallest t wins ties
            bk = (v > bk) ? v : bk;
        }
        for (int off = 32; off; off >>= 1) {
            unsigned long long o = shfl_down_u64(bk, off);
            bk = (o > bk) ? o : bk;
        }
        if (lane == 0) {
            int twin = (int)~(unsigned)(bk & 0xFFFFFFFFull);
            unsigned k32 = (unsigned)(bk >> 32);
            int pwin = base_p + twin;
            part_key[(size_t)(b * NPL_ + bx) * N_ + n] =
                ((unsigned long long)k32 << 32) | (unsigned)~(unsigned)pwin;
        }
    }

    // (4b) LSE + loss
    float ll = 0.0f, pce = 0.0f;
    int np = 0;
    if (valid) {
        int cls = pos ? (lb[bn] + 1) : 0;
        float ssum = 0.0f;
#pragma unroll
        for (int i = 0; i < 21; i++) ssum += __expf(scf[t * 21 + i]);
        float g = scf[t * 21 + cls];
        float lca = fmaxf(__logf(ssum) - g, 0.0f);   // >= 0 by clamp

        mine[(size_t)b * P_ + p0] = pos ? 0.0f : lca;  // coalesced dword

        if (pos) {
            np = 1;
            pce = lca;
            float4 ld = ((const float4*)loc)[(size_t)b * P_ + p0];
            float4 tb = ((const float4*)truths)[b * N_ + bn];
            ll = sl1_encode(ld, pr, tb.x, tb.y, tb.z, tb.w);
        }
    }

    for (int off = 32; off; off >>= 1) {
        ll += __shfl_down(ll, off);
        pce += __shfl_down(pce, off);
        np += __shfl_down(np, off);
    }
    if (lane == 0) { sll[wid] = ll; spc[wid] = pce; snp[wid] = np; }
    __syncthreads();
    if (t == 0) {
        float a = 0.0f, cc = 0.0f;
        int q = 0;
        for (int i = 0; i < 4; i++) { a += sll[i]; cc += spc[i]; q += snp[i]; }
        part_ll[b * NPL_ + bx] = a;
        part_pce[b * NPL_ + bx] = cc;
        part_np[b * NPL_ + bx] = q;
    }
}

// kB: one block per batch. Parallel argmax-partials reduce -> sp[]; parallel
// last-occurrence override deltas; top-k via 31-round bitwise threshold
// search (register compares, no LDS-atomic histograms).
__global__ __launch_bounds__(1024) void
kB_batch(const float* __restrict__ loc,
         const float* __restrict__ conf,
         const float* __restrict__ priors,
         const float* __restrict__ truths,
         const int* __restrict__ labels,
         const float* __restrict__ mine,
         const float* __restrict__ part_ll,
         const float* __restrict__ part_pce,
         const int* __restrict__ part_np,
         const unsigned long long* __restrict__ part_key,
         double* __restrict__ bll,
         double* __restrict__ bpc,
         int* __restrict__ bnp) {
    int b = blockIdx.x, t = threadIdx.x, wid = t >> 6, lane = t & 63;
    __shared__ float tr[N_ * 4];
    __shared__ int lb[N_];
    __shared__ unsigned long long skmax[N_];
    __shared__ int sp[N_];
    __shared__ float sdll, sdpce, sll_s, spc_s;
    __shared__ int sdnp, snp_s;
    __shared__ int scnt[16];
    __shared__ unsigned sT;
    __shared__ float wsum[16];
    __shared__ int wcgt[16];

    if (t < N_ * 4) tr[t] = truths[b * N_ * 4 + t];
    if (t < N_) { lb[t] = labels[b * N_ + t]; skmax[t] = 0ull; }
    if (t == 0) { sdll = 0.f; sdpce = 0.f; sdnp = 0; sll_s = 0.f; spc_s = 0.f; snp_s = 0; }
    __syncthreads();
    // phase 1: parallel reduce of 96 argmax partials per truth (16x16 threads)
    if (t < 256) {
        int n = t & 15, j = t >> 4;
        unsigned long long bk = 0ull;
        for (int i = j; i < NPL_; i += 16) {
            unsigned long long k = part_key[(size_t)(b * NPL_ + i) * N_ + n];
            bk = (k > bk) ? k : bk;
        }
        atomicMax(&skmax[n], bk);
    }
    if (t < NPL_) {                                // partial-sum gather
        atomicAdd(&sll_s, part_ll[b * NPL_ + t]);
        atomicAdd(&spc_s, part_pce[b * NPL_ + t]);
        atomicAdd(&snp_s, part_np[b * NPL_ + t]);
    }
    __syncthreads();
    if (t < N_) sp[t] = (int)~(unsigned)(skmax[t] & 0xFFFFFFFFull);
    __syncthreads();
    // override deltas: (t, sp[t]) contributes iff t is the LAST truth
    // mapping to this prior (sequential last-wins semantics).
    if (t < N_) {
        int p = sp[t];
        bool last = true;
        for (int n = t + 1; n < N_; n++) if (sp[n] == p) last = false;
        if (last) {
            int nf = t;
            float4 pr = ((const float4*)priors)[p];
            float px1 = pr.x - pr.z * 0.5f, py1 = pr.y - pr.w * 0.5f;
            float px2 = pr.x + pr.z * 0.5f, py2 = pr.y + pr.w * 0.5f;
            float ap = (px2 - px1) * (py2 - py1);
            float best = -1.0f;
            int bti = 0;
            for (int n = 0; n < N_; n++) {
                float tx1 = tr[n * 4], ty1 = tr[n * 4 + 1];
                float tx2 = tr[n * 4 + 2], ty2 = tr[n * 4 + 3];
                float at = (tx2 - tx1) * (ty2 - ty1);
                float lx = fmaxf(tx1, px1), ly = fmaxf(ty1, py1);
                float rx = fminf(tx2, px2), ry = fminf(ty2, py2);
                float w = fmaxf(rx - lx, 0.0f), h = fmaxf(ry - ly, 0.0f);
                float inter = w * h;
                float iou = inter / (at + ap - inter);
                if (iou > best) { best = iou; bti = n; }
            }
            int pos_old = (best >= THRESH_) ? 1 : 0;
            const float* cp = conf + ((size_t)b * P_ + p) * C_;
            float x[C_];
            float ssum = 0.0f;
            for (int j = 0; j < C_; j++) { x[j] = cp[j]; ssum += __expf(x[j]); }
            float lse = __logf(ssum);
            float4 ld = ((const float4*)loc)[(size_t)b * P_ + p];
            float dll = sl1_encode(ld, pr, tr[nf * 4], tr[nf * 4 + 1],
                                   tr[nf * 4 + 2], tr[nf * 4 + 3]);
            float dpce = lse - x[lb[nf] + 1];
            int dnp = 1 - pos_old;
            if (pos_old) {
                dll -= sl1_encode(ld, pr, tr[bti * 4], tr[bti * 4 + 1],
                                  tr[bti * 4 + 2], tr[bti * 4 + 3]);
                dpce -= lse - x[lb[bti] + 1];
            }
            atomicAdd(&sdll, dll);
            atomicAdd(&sdpce, dpce);
            atomicAdd(&sdnp, dnp);
        }
    }

    // per-thread override bitmask + register-cached values
    unsigned omask = 0;
#pragma unroll
    for (int n = 0; n < N_; n++) {
        int p = sp[n];
        if ((p & 1023) == t) omask |= 1u << (p >> 10);
    }
    const float* v = mine + (size_t)b * P_;
    int nel = (t < (P_ - 23 * 1024)) ? 24 : 23;
    float xv[24];
#pragma unroll
    for (int i = 0; i < 24; i++) {
        float x = 0.0f;
        if (i < nel) x = v[t + (i << 10)];
        if ((omask >> i) & 1) x = 0.0f;          // overridden -> positive -> 0
        xv[i] = x;
    }
    __syncthreads();                             // sdnp/snp_s complete
    int np = snp_s + sdnp;
    int k = np * 3;
    if (k > P_ - 1) k = P_ - 1;

    // bitwise threshold search: T ends as the k-th largest bit pattern.
    unsigned T = 0u;
    for (int bpos = 30; bpos >= 0; bpos--) {
        unsigned cand = T | (1u << bpos);
        int c = 0;
#pragma unroll
        for (int i = 0; i < 24; i++)
            if (__float_as_uint(xv[i]) >= cand) c++;
        for (int off = 32; off; off >>= 1) c += __shfl_down(c, off);
        if (lane == 0) scnt[wid] = c;
        __syncthreads();
        if (t == 0) {
            int tot = 0;
            for (int i = 0; i < 16; i++) tot += scnt[i];
            sT = (tot >= k) ? cand : T;
        }
        __syncthreads();
        T = sT;
    }

    float psum = 0.0f;
    int cgt = 0;
#pragma unroll
    for (int i = 0; i < 24; i++) {
        if (__float_as_uint(xv[i]) > T) { psum += xv[i]; cgt++; }
    }
    for (int off = 32; off; off >>= 1) {
        psum += __shfl_down(psum, off);
        cgt += __shfl_down(cgt, off);
    }
    if (lane == 0) { wsum[wid] = psum; wcgt[wid] = cgt; }
    __syncthreads();
    if (t == 0) {
        float s2 = 0.0f;
        int cg = 0;
        for (int i = 0; i < 16; i++) { s2 += wsum[i]; cg += wcgt[i]; }
        int skrem = k - cg;                      // >= 0 by construction
        double tot = (double)s2 + (double)skrem * (double)__uint_as_float(T);
        bll[b] = (double)(sll_s + sdll);
        bpc[b] = (double)(spc_s + sdpce) + tot;
        bnp[b] = np;
    }
}

// kC: final 64-wide reduce.
__global__ void kC_final(const double* __restrict__ bll,
                         const double* __restrict__ bpc,
                         const int* __restrict__ bnp,
                         float* __restrict__ out) {
    int t = threadIdx.x;  // 64 threads
    double a = bll[t], c = bpc[t];
    int n = bnp[t];
    for (int off = 32; off; off >>= 1) {
        a += __shfl_down(a, off);
        c += __shfl_down(c, off);
        n += __shfl_down(n, off);
    }
    if (t == 0) {
        double dn = (double)n;
        out[0] = (float)(a / dn);
        out[1] = (float)(c / dn);
    }
}

// ---------------------------------------------------------------- launch

extern "C" void kernel_launch(void* const* d_in, const int* in_sizes, int n_in,
                              void* d_out, int out_size, void* d_ws, size_t ws_size,
                              hipStream_t stream) {
    const float* loc    = (const float*)d_in[0];
    const float* conf   = (const float*)d_in[1];
    const float* priors = (const float*)d_in[2];
    const float* truths = (const float*)d_in[3];
    const int*   labels = (const int*)d_in[4];
    float* out = (float*)d_out;

    char* ws = (char*)d_ws;
    // layout:
    //   [0       .. 786432)   part_key: 64*96*16 u64
    //   [786432  .. 811008)   part_ll:  96*64 floats
    //   [811008  .. 835584)   part_pce: 96*64 floats
    //   [835584  .. 860160)   part_np:  96*64 ints
    //   [860160  .. 860672)   bll: 64 doubles
    //   [860672  .. 861184)   bpc: 64 doubles
    //   [861184  .. 861440)   bnp: 64 ints
    //   [1048576 .. 7336960)  mine: B*P floats
    unsigned long long* part_key = (unsigned long long*)(ws);
    float*  part_ll  = (float*)(ws + 786432);
    float*  part_pce = (float*)(ws + 811008);
    int*    part_np  = (int*)(ws + 835584);
    double* bll      = (double*)(ws + 860160);
    double* bpc      = (double*)(ws + 860672);
    int*    bnp      = (int*)(ws + 861184);
    float*  mine     = (float*)(ws + 1048576);

    hipLaunchKernelGGL(kF_fused, dim3(NPL_, B_), dim3(256), 0, stream,
                       loc, conf, priors, truths, labels,
                       mine, part_ll, part_pce, part_np, part_key);
    hipLaunchKernelGGL(kB_batch, dim3(B_), dim3(1024), 0, stream,
                       loc, conf, priors, truths, labels, mine,
                       part_ll, part_pce, part_np, part_key, bll, bpc, bnp);
    hipLaunchKernelGGL(kC_final, dim3(1), dim3(64), 0, stream, bll, bpc, bnp, out);
}